// Round 18
// baseline (126.475 us; speedup 1.0000x reference)
//
#include <hip/hip_runtime.h>
#include <hip/hip_bf16.h>
#include <string.h>

#define NN 100000
#define NE 1600000
#define INF_ 128
#define OC 128   // NHEAD*OUT_F
#define NH 4
#define ALPHA 0.2f
#define LDA 272                      // GEMM LDS row stride in bytes

#define BSH 7
#define BINW 128                     // nodes per bin
#define NBIN ((NN + BINW - 1) / BINW)   // 782
#define CAPB 2560                    // padded per-bin capacity (mean 2046, sigma~45)
#define SCOLS_CAP (CAPB + 3 * BINW / 2 + 16)  // aligned-start fill + overhang
#define EPT 16                       // edges per thread, partition kernels
#define EPB (256 * EPT)              // 4096 edges per block
#define NPB1 ((NE + EPB - 1) / EPB)  // 391 blocks
#define NGB  ((NN + 127) / 128)      // 782 gemm blocks (128 rows each)

typedef __bf16 bf16x8 __attribute__((ext_vector_type(8)));
typedef float f32x4 __attribute__((ext_vector_type(4)));
typedef float f32x2 __attribute__((ext_vector_type(2)));

__device__ __forceinline__ float lrelu(float x) {
    return x > 0.0f ? x : ALPHA * x;
}
__device__ __forceinline__ unsigned short f2bf(float f) {
    __hip_bfloat16 b = __float2bfloat16(f);
    unsigned short u; memcpy(&u, &b, 2); return u;
}
__device__ __forceinline__ int sel4(const int4 v, int j) {
    const int lo = (j & 1) ? v.y : v.x;
    const int hi = (j & 1) ? v.w : v.z;
    return (j & 2) ? hi : lo;
}

// Pre-pass (72 blocks): blocks 0-63 transpose+convert W -> Wt[col][k];
// blocks 64-71 build extra B-columns 128..135 = wl|wr folds, 136..143 zero.
// Block 0 inits padded bin cursors.
__global__ __launch_bounds__(256) void k_pre(
    const float* __restrict__ W, const float* __restrict__ a_l,
    const float* __restrict__ a_r, __hip_bfloat16* __restrict__ Wt,
    int* __restrict__ bincur) {
    const int t = threadIdx.x;
    const int b = blockIdx.x;
    if (b < 64) {
        const int i = b * 256 + t;            // < 16384
        const int co = i >> 7, ko = i & 127;
        Wt[i] = __float2bfloat16(W[ko * OC + co]);
    } else {
        const int i = (b - 64) * 256 + t;     // < 2048
        const int cp = i >> 7, k = i & 127;   // cp 0..15
        float v = 0.f;
        if (cp < 8) {
            const int hd = cp & 3;
            const float* av = (cp < 4) ? a_l : a_r;
#pragma unroll 8
            for (int j = 0; j < 32; ++j)
                v += W[k * OC + hd * 32 + j] * av[hd * 32 + j];
        }
        Wt[(128 + cp) * 128 + k] = __float2bfloat16(v);
    }
    if (b == 0)
        for (int i = t; i < NBIN; i += 256) bincur[i] = i * CAPB;
}

// Mega-kernel: gemm blocks (bid%3 < 2, 128 rows each, staged sB shared by
// two 64-row tiles) and part1 blocks (bid%3 == 2).
__global__ __launch_bounds__(256) void k_gp1(
    const float* __restrict__ x, const __hip_bfloat16* __restrict__ Wt,
    __hip_bfloat16* __restrict__ hb, float* __restrict__ al, float* __restrict__ ar,
    const int* __restrict__ row, const int* __restrict__ col,
    int* __restrict__ bincur, unsigned* __restrict__ tmp) {
    __shared__ __align__(16) char smem[144 * LDA];   // 38.3 KB, carved per role
    const int tid = threadIdx.x;
    const int m3 = blockIdx.x % 3;

    if (m3 != 2) {
        // ---- GEMM path: [h | al | ar] = x @ [W | wl | wr], 2 tiles ----
        char* sB = smem;                                  // Wt [col][k], 144 rows
        const int gi = (blockIdx.x / 3) * 2 + m3;         // 0..781
        const int rowBase0 = gi * 128;

        for (int i4 = tid; i4 < 144 * 16; i4 += 256) {
            const int c = i4 >> 4, k4 = i4 & 15;
            *(uint4*)(sB + c * LDA + k4 * 16) =
                *(const uint4*)((const char*)Wt + (size_t)c * 256 + k4 * 16);
        }
        __syncthreads();

        const int lane = tid & 63;
        const int w = tid >> 6;
        const int koff8 = (lane >> 4) * 8;
        const int koff = (lane >> 4) * 16;

        for (int tile = 0; tile < 2; ++tile) {
            const int rowBase = rowBase0 + tile * 64;
            const int arow = w * 16 + (lane & 15);
            const int grow = rowBase + arow;
            const int growc = (grow < NN) ? grow : (NN - 1);

            f32x4 acc[9];
#pragma unroll
            for (int n = 0; n < 9; ++n) acc[n] = (f32x4){0.f, 0.f, 0.f, 0.f};

#pragma unroll
            for (int kk = 0; kk < 4; ++kk) {
                const float* xp = x + (size_t)growc * INF_ + kk * 32 + koff8;
                const float4 f0 = *(const float4*)xp;
                const float4 f1 = *(const float4*)(xp + 4);
                union { bf16x8 v; unsigned short u[8]; } au;
                au.u[0] = f2bf(f0.x); au.u[1] = f2bf(f0.y);
                au.u[2] = f2bf(f0.z); au.u[3] = f2bf(f0.w);
                au.u[4] = f2bf(f1.x); au.u[5] = f2bf(f1.y);
                au.u[6] = f2bf(f1.z); au.u[7] = f2bf(f1.w);
#pragma unroll
                for (int n = 0; n < 9; ++n) {
                    const int brow = n * 16 + (lane & 15);
                    const bf16x8 b = *(const bf16x8*)(sB + brow * LDA + kk * 64 + koff);
                    acc[n] = __builtin_amdgcn_mfma_f32_16x16x32_bf16(au.v, b, acc[n], 0, 0, 0);
                }
            }

            const int rbase = rowBase + w * 16 + (lane >> 4) * 4;
#pragma unroll
            for (int n = 0; n < 8; ++n) {
                const int cc = n * 16 + (lane & 15);
#pragma unroll
                for (int r = 0; r < 4; ++r) {
                    const int rw = rbase + r;
                    if (rw < NN) hb[(size_t)rw * OC + cc] = __float2bfloat16(acc[n][r]);
                }
            }
            const int cp = lane & 15;
            if (cp < 8) {
                const int hd = cp & 3;
                float* dst = (cp < 4) ? al : ar;
#pragma unroll
                for (int r = 0; r < 4; ++r) {
                    const int rw = rbase + r;
                    if (rw < NN) dst[rw * NH + hd] = acc[8][r];
                }
            }
        }
    } else {
        // ---- part1 path: coarse partition into bin-grouped packed words ----
        int* h     = (int*)smem;
        int* gbase = h + NBIN;
        int* lcur  = gbase + NBIN;
        const int pb = blockIdx.x / 3;    // 0..390
        const int t = tid;
        for (int i = t; i < NBIN; i += 256) { h[i] = 0; lcur[i] = 0; }
        __syncthreads();

        const int e0 = pb * EPB + t * EPT;
        int r[EPT], c[EPT];
        if (e0 + EPT <= NE) {
#pragma unroll
            for (int q = 0; q < EPT / 4; ++q) {
                const int4 rv = *(const int4*)&row[e0 + q * 4];
                const int4 cv = *(const int4*)&col[e0 + q * 4];
                r[q*4+0] = rv.x; r[q*4+1] = rv.y; r[q*4+2] = rv.z; r[q*4+3] = rv.w;
                c[q*4+0] = cv.x; c[q*4+1] = cv.y; c[q*4+2] = cv.z; c[q*4+3] = cv.w;
            }
        } else {
#pragma unroll
            for (int i = 0; i < EPT; ++i) {
                const int e = e0 + i;
                r[i] = (e < NE) ? row[e] : -1;
                c[i] = (e < NE) ? col[e] : 0;
            }
        }
#pragma unroll
        for (int i = 0; i < EPT; ++i)
            if (r[i] >= 0) atomicAdd(&h[r[i] >> BSH], 1);
        __syncthreads();
        for (int i = t; i < NBIN; i += 256)
            if (h[i]) gbase[i] = atomicAdd(&bincur[i], h[i]);
        __syncthreads();
#pragma unroll
        for (int i = 0; i < EPT; ++i) {
            if (r[i] < 0) continue;
            const int b = r[i] >> BSH;
            const int pos = atomicAdd(&lcur[b], 1);
            tmp[gbase[b] + pos] =
                ((unsigned)(r[i] & (BINW - 1)) << 17) | (unsigned)c[i];
        }
    }
}

// Fused fine-partition + aggregation: one 512-thread block per bin.
__global__ __launch_bounds__(512) void k_p2agg(
    const unsigned* __restrict__ tmp, const int* __restrict__ bincur,
    const float* __restrict__ al, const float* __restrict__ ar,
    const __hip_bfloat16* __restrict__ hb, float* __restrict__ out) {
    __shared__ __align__(16) unsigned stage[CAPB];      // 10.2 KB
    __shared__ __align__(16) int scols[SCOLS_CAP];      // 12.0 KB
    __shared__ int h[BINW], st[BINW], cur[BINW], ts[BINW];
    const int b = blockIdx.x;
    const int t = threadIdx.x;                          // 0..511
    const int gs = b * CAPB;
    const int cnt = bincur[b] - gs;

    if (t < BINW) h[t] = 0;
    __syncthreads();
    for (int j = t; j < cnt; j += 512) {
        const unsigned p = tmp[gs + j];
        stage[j] = p;
        atomicAdd(&h[p >> 17], 1);
    }
    __syncthreads();
    if (t < BINW) ts[t] = (h[t] + 3) & ~3;
    __syncthreads();
    for (int o = 1; o < BINW; o <<= 1) {
        const int add = (t >= o && t < BINW) ? ts[t - o] : 0;
        __syncthreads();
        if (t < BINW) ts[t] += add;
        __syncthreads();
    }
    if (t < BINW) {
        const int s = ts[t] - ((h[t] + 3) & ~3);
        st[t] = s;
        cur[t] = s;
    }
    __syncthreads();
    for (int j = t; j < cnt; j += 512) {
        const unsigned p = stage[j];
        const int pos = atomicAdd(&cur[p >> 17], 1);
        scols[pos] = (int)(p & 0x1FFFFu);
    }
    __syncthreads();

    const int w = t >> 6;
    const int lane = t & 63;
    const int g = lane >> 4;
    const int sl = lane & 15;
    const int hsel = sl >> 2;
    const int je = sl >> 2;
    const int sh = sl & 3;
    const int sbase = lane & 48;
    const char* hrow = (const char*)hb + sl * 16;

    for (int rnd = 0; rnd < BINW / 32; ++rnd) {
        const int ln = rnd * 32 + w * 4 + g;
        const int node = b * BINW + ln;
        if (node >= NN) continue;
        const int start = st[ln];
        const int deg = h[ln];
        const float al_sh = al[node * NH + sh];

        f32x2 a0 = {0.f, 0.f}, a1 = {0.f, 0.f}, a2 = {0.f, 0.f}, a3 = {0.f, 0.f};
        float ssum = 0.f;

        int4 cA = *(const int4*)(scols + start);
        int4 cB = *(const int4*)(scols + start + 4);

        for (int kk = 0; kk < deg; kk += 8) {
            const int rem = deg - kk;
            const int4 cA2 = *(const int4*)(scols + start + kk + 8);
            const int4 cB2 = *(const int4*)(scols + start + kk + 12);

            float wvA = 0.f, wvB = 0.f;
            if (je < rem) {
                const int c = sel4(cA, je);
                wvA = __expf(lrelu(al_sh + ar[c * NH + sh]));
            }
            if (je + 4 < rem) {
                const int c = sel4(cB, je);
                wvB = __expf(lrelu(al_sh + ar[c * NH + sh]));
            }

            int c_[8] = {cA.x, cA.y, cA.z, cA.w, cB.x, cB.y, cB.z, cB.w};
#pragma unroll
            for (int j = 0; j < 8; ++j)
                if (j >= rem) c_[j] = 0;

#pragma unroll
            for (int j = 0; j < 8; ++j) {
                const float wj = __shfl(j < 4 ? wvA : wvB, sbase + (j & 3) * 4 + hsel);
                const uint4 v = *(const uint4*)(hrow + (size_t)c_[j] * 256);
                a0 += wj * (f32x2){__uint_as_float(v.x << 16), __uint_as_float(v.x & 0xffff0000u)};
                a1 += wj * (f32x2){__uint_as_float(v.y << 16), __uint_as_float(v.y & 0xffff0000u)};
                a2 += wj * (f32x2){__uint_as_float(v.z << 16), __uint_as_float(v.z & 0xffff0000u)};
                a3 += wj * (f32x2){__uint_as_float(v.w << 16), __uint_as_float(v.w & 0xffff0000u)};
                ssum += wj;
            }
            cA = cA2; cB = cB2;
        }

        const float inv = (ssum > 0.f) ? 1.0f / ssum : 0.f;
        float4 o0, o1;
        o0.x = a0.x * inv; o0.y = a0.y * inv; o0.z = a1.x * inv; o0.w = a1.y * inv;
        o1.x = a2.x * inv; o1.y = a2.y * inv; o1.z = a3.x * inv; o1.w = a3.y * inv;
        float* dst = out + (size_t)node * OC + sl * 8;
        *(float4*)dst = o0;
        *(float4*)(dst + 4) = o1;
    }
}

extern "C" void kernel_launch(void* const* d_in, const int* in_sizes, int n_in,
                              void* d_out, int out_size, void* d_ws, size_t ws_size,
                              hipStream_t stream) {
    const float* x    = (const float*)d_in[0];
    const int*   ei   = (const int*)d_in[1];    // [2, NE]
    const float* W    = (const float*)d_in[2];
    const float* a_l  = (const float*)d_in[3];
    const float* a_r  = (const float*)d_in[4];
    float* out = (float*)d_out;

    const int* row = ei;         // destination
    const int* col = ei + NE;    // source

    char* ws = (char*)d_ws;
    __hip_bfloat16* hb = (__hip_bfloat16*)ws;   ws += (size_t)NN * OC * 2;      // 25.6 MB
    __hip_bfloat16* Wt = (__hip_bfloat16*)ws;   ws += (size_t)144 * 128 * 2;    // 36 KB
    float*    al      = (float*)ws;             ws += (size_t)NN * NH * 4;
    float*    ar      = (float*)ws;             ws += (size_t)NN * NH * 4;
    unsigned* tmp     = (unsigned*)ws;          ws += (size_t)NBIN * CAPB * 4;  // 8.0 MB
    int*      bincur  = (int*)ws;               ws += (size_t)NBIN * 4;

    k_pre<<<72, 256, 0, stream>>>(W, a_l, a_r, Wt, bincur);
    k_gp1<<<3 * NPB1, 256, 0, stream>>>(x, Wt, hb, al, ar, row, col, bincur, tmp);
    k_p2agg<<<NBIN, 512, 0, stream>>>(tmp, bincur, al, ar, hb, out);
}

// Round 19
// 126.359 us; speedup vs baseline: 1.0009x; 1.0009x over previous
//
#include <hip/hip_runtime.h>
#include <hip/hip_bf16.h>
#include <string.h>

#define NN 100000
#define NE 1600000
#define INF_ 128
#define OC 128   // NHEAD*OUT_F
#define NH 4
#define ALPHA 0.2f
#define LDA 272                      // GEMM LDS row stride in bytes

#define BSH 7
#define BINW 128                     // nodes per bin
#define NBIN ((NN + BINW - 1) / BINW)   // 782
#define NBIN4 784                    // rounded to x4 for the hp mapping
#define CAPB 2560                    // padded per-bin capacity (mean 2046, sigma~45)
#define SCOLS_CAP (CAPB + 3 * BINW / 2 + 16)
#define EPT 16                       // edges per thread, partition kernels
#define EPB (256 * EPT)              // 4096 edges per block
#define NPB1 ((NE + EPB - 1) / EPB)  // 391 blocks

typedef __bf16 bf16x8 __attribute__((ext_vector_type(8)));
typedef float f32x4 __attribute__((ext_vector_type(4)));
typedef float f32x2 __attribute__((ext_vector_type(2)));

__device__ __forceinline__ float lrelu(float x) {
    return x > 0.0f ? x : ALPHA * x;
}
__device__ __forceinline__ unsigned short f2bf(float f) {
    __hip_bfloat16 b = __float2bfloat16(f);
    unsigned short u; memcpy(&u, &b, 2); return u;
}
__device__ __forceinline__ int sel4(const int4 v, int j) {
    const int lo = (j & 1) ? v.y : v.x;
    const int hi = (j & 1) ? v.w : v.z;
    return (j & 2) ? hi : lo;
}

// Pre-pass (72 blocks): blocks 0-63 transpose+convert W -> Wt[col][k];
// blocks 64-71 build extra B-columns 128..135 = wl|wr folds, 136..143 zero.
// Block 0 inits padded bin cursors.
__global__ __launch_bounds__(256) void k_pre(
    const float* __restrict__ W, const float* __restrict__ a_l,
    const float* __restrict__ a_r, __hip_bfloat16* __restrict__ Wt,
    int* __restrict__ bincur) {
    const int t = threadIdx.x;
    const int b = blockIdx.x;
    if (b < 64) {
        const int i = b * 256 + t;            // < 16384
        const int co = i >> 7, ko = i & 127;
        Wt[i] = __float2bfloat16(W[ko * OC + co]);
    } else {
        const int i = (b - 64) * 256 + t;     // < 2048
        const int cp = i >> 7, k = i & 127;   // cp 0..15
        float v = 0.f;
        if (cp < 8) {
            const int hd = cp & 3;
            const float* av = (cp < 4) ? a_l : a_r;
#pragma unroll 8
            for (int j = 0; j < 32; ++j)
                v += W[k * OC + hd * 32 + j] * av[hd * 32 + j];
        }
        Wt[(128 + cp) * 128 + k] = __float2bfloat16(v);
    }
    if (b == 0)
        for (int i = t; i < NBIN; i += 256) bincur[i] = i * CAPB;
}

// Mega-kernel (R17 form): gemm blocks (bid%5 != 4) and part1 (bid%5 == 4).
// GEMM writes h split by head-pair: hb0 = heads 0-1 (cols 0..63),
// hb1 = heads 2-3 (cols 64..127); each row is 128B.
__global__ __launch_bounds__(256) void k_gp1(
    const float* __restrict__ x, const __hip_bfloat16* __restrict__ Wt,
    __hip_bfloat16* __restrict__ hb0, __hip_bfloat16* __restrict__ hb1,
    float* __restrict__ al, float* __restrict__ ar,
    const int* __restrict__ row, const int* __restrict__ col,
    int* __restrict__ bincur, unsigned* __restrict__ tmp) {
    __shared__ __align__(16) char smem[144 * LDA];   // 38.3 KB, carved per role
    const int tid = threadIdx.x;
    const int m5 = blockIdx.x % 5;

    if (m5 != 4) {
        // ---- GEMM path: [h | al | ar] = x @ [W | wl | wr] ----
        char* sB = smem;                                  // Wt [col][k], 144 rows
        const int gb = (blockIdx.x / 5) * 4 + m5;         // 0..1563 (1563 = spare)
        const int rowBase = gb * 64;

        for (int i4 = tid; i4 < 144 * 16; i4 += 256) {
            const int c = i4 >> 4, k4 = i4 & 15;
            *(uint4*)(sB + c * LDA + k4 * 16) =
                *(const uint4*)((const char*)Wt + (size_t)c * 256 + k4 * 16);
        }
        __syncthreads();

        const int lane = tid & 63;
        const int w = tid >> 6;
        const int arow = w * 16 + (lane & 15);
        const int grow = rowBase + arow;
        const int growc = (grow < NN) ? grow : (NN - 1);
        const int koff8 = (lane >> 4) * 8;
        const int koff = (lane >> 4) * 16;

        f32x4 acc[9];
#pragma unroll
        for (int n = 0; n < 9; ++n) acc[n] = (f32x4){0.f, 0.f, 0.f, 0.f};

#pragma unroll
        for (int kk = 0; kk < 4; ++kk) {
            const float* xp = x + (size_t)growc * INF_ + kk * 32 + koff8;
            const float4 f0 = *(const float4*)xp;
            const float4 f1 = *(const float4*)(xp + 4);
            union { bf16x8 v; unsigned short u[8]; } au;
            au.u[0] = f2bf(f0.x); au.u[1] = f2bf(f0.y);
            au.u[2] = f2bf(f0.z); au.u[3] = f2bf(f0.w);
            au.u[4] = f2bf(f1.x); au.u[5] = f2bf(f1.y);
            au.u[6] = f2bf(f1.z); au.u[7] = f2bf(f1.w);
#pragma unroll
            for (int n = 0; n < 9; ++n) {
                const int brow = n * 16 + (lane & 15);
                const bf16x8 b = *(const bf16x8*)(sB + brow * LDA + kk * 64 + koff);
                acc[n] = __builtin_amdgcn_mfma_f32_16x16x32_bf16(au.v, b, acc[n], 0, 0, 0);
            }
        }

        const int rbase = rowBase + w * 16 + (lane >> 4) * 4;
#pragma unroll
        for (int n = 0; n < 8; ++n) {
            const int cc = (n * 16 + (lane & 15)) & 63;
            __hip_bfloat16* hbn = (n < 4) ? hb0 : hb1;
#pragma unroll
            for (int r = 0; r < 4; ++r) {
                const int rw = rbase + r;
                if (rw < NN) hbn[(size_t)rw * 64 + cc] = __float2bfloat16(acc[n][r]);
            }
        }
        const int cp = lane & 15;
        if (cp < 8) {
            const int hd = cp & 3;
            float* dst = (cp < 4) ? al : ar;
#pragma unroll
            for (int r = 0; r < 4; ++r) {
                const int rw = rbase + r;
                if (rw < NN) dst[rw * NH + hd] = acc[8][r];
            }
        }
    } else {
        // ---- part1 path: coarse partition into bin-grouped packed words ----
        int* h     = (int*)smem;
        int* gbase = h + NBIN;
        int* lcur  = gbase + NBIN;
        const int pb = blockIdx.x / 5;    // 0..390
        const int t = tid;
        for (int i = t; i < NBIN; i += 256) { h[i] = 0; lcur[i] = 0; }
        __syncthreads();

        const int e0 = pb * EPB + t * EPT;
        int r[EPT], c[EPT];
        if (e0 + EPT <= NE) {
#pragma unroll
            for (int q = 0; q < EPT / 4; ++q) {
                const int4 rv = *(const int4*)&row[e0 + q * 4];
                const int4 cv = *(const int4*)&col[e0 + q * 4];
                r[q*4+0] = rv.x; r[q*4+1] = rv.y; r[q*4+2] = rv.z; r[q*4+3] = rv.w;
                c[q*4+0] = cv.x; c[q*4+1] = cv.y; c[q*4+2] = cv.z; c[q*4+3] = cv.w;
            }
        } else {
#pragma unroll
            for (int i = 0; i < EPT; ++i) {
                const int e = e0 + i;
                r[i] = (e < NE) ? row[e] : -1;
                c[i] = (e < NE) ? col[e] : 0;
            }
        }
#pragma unroll
        for (int i = 0; i < EPT; ++i)
            if (r[i] >= 0) atomicAdd(&h[r[i] >> BSH], 1);
        __syncthreads();
        for (int i = t; i < NBIN; i += 256)
            if (h[i]) gbase[i] = atomicAdd(&bincur[i], h[i]);
        __syncthreads();
#pragma unroll
        for (int i = 0; i < EPT; ++i) {
            if (r[i] < 0) continue;
            const int b = r[i] >> BSH;
            const int pos = atomicAdd(&lcur[b], 1);
            tmp[gbase[b] + pos] =
                ((unsigned)(r[i] & (BINW - 1)) << 17) | (unsigned)c[i];
        }
    }
}

// Fused fine-partition + aggregation, head-pair sharded.
// Grid 2*NBIN4 blocks: xcd = bid&7; hp = xcd>>2; bin = (bid>>3)*4 + (xcd&3).
// With round-robin block->XCD dispatch, XCDs 0-3 only read hb0, 4-7 only hb1
// (correctness does not depend on this; only locality does).
// 8-lane group per node: lane sl owns dims [hp*64 + sl*8, +8).
__global__ __launch_bounds__(512) void k_p2agg(
    const unsigned* __restrict__ tmp, const int* __restrict__ bincur,
    const float* __restrict__ al, const float* __restrict__ ar,
    const __hip_bfloat16* __restrict__ hb0, const __hip_bfloat16* __restrict__ hb1,
    float* __restrict__ out) {
    __shared__ __align__(16) unsigned stage[CAPB];      // 10.2 KB
    __shared__ __align__(16) int scols[SCOLS_CAP];      // 11.1 KB
    __shared__ int h[BINW], st[BINW], cur[BINW], ts[BINW];
    const int xcd = blockIdx.x & 7;
    const int hp  = xcd >> 2;
    const int b   = ((blockIdx.x >> 3) << 2) + (xcd & 3);
    if (b >= NBIN) return;
    const int t = threadIdx.x;                          // 0..511
    const int gs = b * CAPB;
    const int cnt = bincur[b] - gs;

    if (t < BINW) h[t] = 0;
    __syncthreads();
    for (int j = t; j < cnt; j += 512) {
        const unsigned p = tmp[gs + j];
        stage[j] = p;
        atomicAdd(&h[p >> 17], 1);
    }
    __syncthreads();
    if (t < BINW) ts[t] = (h[t] + 3) & ~3;
    __syncthreads();
    for (int o = 1; o < BINW; o <<= 1) {
        const int add = (t >= o && t < BINW) ? ts[t - o] : 0;
        __syncthreads();
        if (t < BINW) ts[t] += add;
        __syncthreads();
    }
    if (t < BINW) {
        const int s = ts[t] - ((h[t] + 3) & ~3);
        st[t] = s;
        cur[t] = s;
    }
    __syncthreads();
    for (int j = t; j < cnt; j += 512) {
        const unsigned p = stage[j];
        const int pos = atomicAdd(&cur[p >> 17], 1);
        scols[pos] = (int)(p & 0x1FFFFu);
    }
    __syncthreads();

    // Phase 2: 8 waves x 8 groups of 8 lanes = 64 nodes/round, 2 rounds.
    const int w = t >> 6;
    const int lane = t & 63;
    const int g = lane >> 3;            // group within wave (0..7)
    const int sl = lane & 7;            // sublane within group
    const int hh = sl >> 2;             // head-within-pair this lane accumulates
    const int je = sl >> 1;             // edge slot this lane scores (0..3)
    const int sh = hp * 2 + (sl & 1);   // head this lane scores
    const int sbase = lane & 56;        // group base lane
    const __hip_bfloat16* hbh = hp ? hb1 : hb0;
    const char* hrow = (const char*)hbh + sl * 16;   // lane's 16B slice of 128B row

    for (int rnd = 0; rnd < BINW / 64; ++rnd) {
        const int ln = rnd * 64 + w * 8 + g;
        const int node = b * BINW + ln;
        if (node >= NN) continue;
        const int start = st[ln];
        const int deg = h[ln];
        const float al_sh = al[node * NH + sh];

        f32x2 a0 = {0.f, 0.f}, a1 = {0.f, 0.f}, a2 = {0.f, 0.f}, a3 = {0.f, 0.f};
        float ssum = 0.f;

        int4 cA = *(const int4*)(scols + start);
        int4 cB = *(const int4*)(scols + start + 4);

        for (int kk = 0; kk < deg; kk += 8) {
            const int rem = deg - kk;
            const int4 cA2 = *(const int4*)(scols + start + kk + 8);
            const int4 cB2 = *(const int4*)(scols + start + kk + 12);

            float wvA = 0.f, wvB = 0.f;
            if (je < rem) {
                const int c = sel4(cA, je);
                wvA = __expf(lrelu(al_sh + ar[c * NH + sh]));
            }
            if (je + 4 < rem) {
                const int c = sel4(cB, je);
                wvB = __expf(lrelu(al_sh + ar[c * NH + sh]));
            }

            int c_[8] = {cA.x, cA.y, cA.z, cA.w, cB.x, cB.y, cB.z, cB.w};
#pragma unroll
            for (int j = 0; j < 8; ++j)
                if (j >= rem) c_[j] = 0;

#pragma unroll
            for (int j = 0; j < 8; ++j) {
                const float wj = __shfl(j < 4 ? wvA : wvB, sbase + (j & 3) * 2 + hh);
                const uint4 v = *(const uint4*)(hrow + (size_t)c_[j] * 128);
                a0 += wj * (f32x2){__uint_as_float(v.x << 16), __uint_as_float(v.x & 0xffff0000u)};
                a1 += wj * (f32x2){__uint_as_float(v.y << 16), __uint_as_float(v.y & 0xffff0000u)};
                a2 += wj * (f32x2){__uint_as_float(v.z << 16), __uint_as_float(v.z & 0xffff0000u)};
                a3 += wj * (f32x2){__uint_as_float(v.w << 16), __uint_as_float(v.w & 0xffff0000u)};
                ssum += wj;
            }
            cA = cA2; cB = cB2;
        }

        const float inv = (ssum > 0.f) ? 1.0f / ssum : 0.f;
        float4 o0, o1;
        o0.x = a0.x * inv; o0.y = a0.y * inv; o0.z = a1.x * inv; o0.w = a1.y * inv;
        o1.x = a2.x * inv; o1.y = a2.y * inv; o1.z = a3.x * inv; o1.w = a3.y * inv;
        float* dst = out + (size_t)node * OC + hp * 64 + sl * 8;
        *(float4*)dst = o0;
        *(float4*)(dst + 4) = o1;
    }
}

extern "C" void kernel_launch(void* const* d_in, const int* in_sizes, int n_in,
                              void* d_out, int out_size, void* d_ws, size_t ws_size,
                              hipStream_t stream) {
    const float* x    = (const float*)d_in[0];
    const int*   ei   = (const int*)d_in[1];    // [2, NE]
    const float* W    = (const float*)d_in[2];
    const float* a_l  = (const float*)d_in[3];
    const float* a_r  = (const float*)d_in[4];
    float* out = (float*)d_out;

    const int* row = ei;         // destination
    const int* col = ei + NE;    // source

    char* ws = (char*)d_ws;
    __hip_bfloat16* hb0 = (__hip_bfloat16*)ws;  ws += (size_t)NN * 64 * 2;      // 12.8 MB
    __hip_bfloat16* hb1 = (__hip_bfloat16*)ws;  ws += (size_t)NN * 64 * 2;      // 12.8 MB
    __hip_bfloat16* Wt = (__hip_bfloat16*)ws;   ws += (size_t)144 * 128 * 2;    // 36 KB
    float*    al      = (float*)ws;             ws += (size_t)NN * NH * 4;
    float*    ar      = (float*)ws;             ws += (size_t)NN * NH * 4;
    unsigned* tmp     = (unsigned*)ws;          ws += (size_t)NBIN * CAPB * 4;  // 8.0 MB
    int*      bincur  = (int*)ws;               ws += (size_t)NBIN * 4;

    k_pre<<<72, 256, 0, stream>>>(W, a_l, a_r, Wt, bincur);
    k_gp1<<<1955, 256, 0, stream>>>(x, Wt, hb0, hb1, al, ar, row, col, bincur, tmp);
    k_p2agg<<<2 * NBIN4, 512, 0, stream>>>(tmp, bincur, al, ar, hb0, hb1, out);
}

// Round 20
// 123.499 us; speedup vs baseline: 1.0241x; 1.0232x over previous
//
#include <hip/hip_runtime.h>
#include <hip/hip_bf16.h>
#include <string.h>

#define NN 100000
#define NE 1600000
#define INF_ 128
#define OC 128   // NHEAD*OUT_F
#define NH 4
#define ALPHA 0.2f
#define LDA 272                      // GEMM LDS row stride in bytes

#define BSH 7
#define BINW 128                     // nodes per bin
#define NBIN ((NN + BINW - 1) / BINW)   // 782
#define CAPB 2560                    // padded per-bin capacity (mean 2046, sigma~45)
#define SCOLS_CAP (CAPB + 3 * BINW / 2 + 16)  // aligned-start fill + overhang
#define EPT 16                       // edges per thread, partition kernels
#define EPB (256 * EPT)              // 4096 edges per block
#define NPB1 ((NE + EPB - 1) / EPB)  // 391 blocks

typedef __bf16 bf16x8 __attribute__((ext_vector_type(8)));
typedef float f32x4 __attribute__((ext_vector_type(4)));
typedef float f32x2 __attribute__((ext_vector_type(2)));

__device__ __forceinline__ float lrelu(float x) {
    return x > 0.0f ? x : ALPHA * x;
}
__device__ __forceinline__ unsigned short f2bf(float f) {
    __hip_bfloat16 b = __float2bfloat16(f);
    unsigned short u; memcpy(&u, &b, 2); return u;
}
__device__ __forceinline__ int sel4(const int4 v, int j) {
    const int lo = (j & 1) ? v.y : v.x;
    const int hi = (j & 1) ? v.w : v.z;
    return (j & 2) ? hi : lo;
}

// Pre-pass (72 blocks): blocks 0-63 transpose+convert W -> Wt[col][k];
// blocks 64-71 build extra B-columns 128..135 = wl|wr folds, 136..143 zero.
// Block 0 inits padded bin cursors.
__global__ __launch_bounds__(256) void k_pre(
    const float* __restrict__ W, const float* __restrict__ a_l,
    const float* __restrict__ a_r, __hip_bfloat16* __restrict__ Wt,
    int* __restrict__ bincur) {
    const int t = threadIdx.x;
    const int b = blockIdx.x;
    if (b < 64) {
        const int i = b * 256 + t;            // < 16384
        const int co = i >> 7, ko = i & 127;
        Wt[i] = __float2bfloat16(W[ko * OC + co]);
    } else {
        const int i = (b - 64) * 256 + t;     // < 2048
        const int cp = i >> 7, k = i & 127;   // cp 0..15
        float v = 0.f;
        if (cp < 8) {
            const int hd = cp & 3;
            const float* av = (cp < 4) ? a_l : a_r;
#pragma unroll 8
            for (int j = 0; j < 32; ++j)
                v += W[k * OC + hd * 32 + j] * av[hd * 32 + j];
        }
        Wt[(128 + cp) * 128 + k] = __float2bfloat16(v);
    }
    if (b == 0)
        for (int i = t; i < NBIN; i += 256) bincur[i] = i * CAPB;
}

// Mega-kernel: gemm blocks (bid%5 != 4) and part1 blocks (bid%5 == 4).
__global__ __launch_bounds__(256) void k_gp1(
    const float* __restrict__ x, const __hip_bfloat16* __restrict__ Wt,
    __hip_bfloat16* __restrict__ hb, float* __restrict__ al, float* __restrict__ ar,
    const int* __restrict__ row, const int* __restrict__ col,
    int* __restrict__ bincur, unsigned* __restrict__ tmp) {
    __shared__ __align__(16) char smem[144 * LDA];   // 38.3 KB, carved per role
    const int tid = threadIdx.x;
    const int m5 = blockIdx.x % 5;

    if (m5 != 4) {
        // ---- GEMM path: [h | al | ar] = x @ [W | wl | wr] ----
        char* sB = smem;                                  // Wt [col][k], 144 rows
        const int gb = (blockIdx.x / 5) * 4 + m5;         // 0..1563 (1563 = spare)
        const int rowBase = gb * 64;

        for (int i4 = tid; i4 < 144 * 16; i4 += 256) {
            const int c = i4 >> 4, k4 = i4 & 15;
            *(uint4*)(sB + c * LDA + k4 * 16) =
                *(const uint4*)((const char*)Wt + (size_t)c * 256 + k4 * 16);
        }
        __syncthreads();

        const int lane = tid & 63;
        const int w = tid >> 6;
        const int arow = w * 16 + (lane & 15);
        const int grow = rowBase + arow;
        const int growc = (grow < NN) ? grow : (NN - 1);
        const int koff8 = (lane >> 4) * 8;
        const int koff = (lane >> 4) * 16;

        f32x4 acc[9];
#pragma unroll
        for (int n = 0; n < 9; ++n) acc[n] = (f32x4){0.f, 0.f, 0.f, 0.f};

#pragma unroll
        for (int kk = 0; kk < 4; ++kk) {
            const float* xp = x + (size_t)growc * INF_ + kk * 32 + koff8;
            const float4 f0 = *(const float4*)xp;
            const float4 f1 = *(const float4*)(xp + 4);
            union { bf16x8 v; unsigned short u[8]; } au;
            au.u[0] = f2bf(f0.x); au.u[1] = f2bf(f0.y);
            au.u[2] = f2bf(f0.z); au.u[3] = f2bf(f0.w);
            au.u[4] = f2bf(f1.x); au.u[5] = f2bf(f1.y);
            au.u[6] = f2bf(f1.z); au.u[7] = f2bf(f1.w);
#pragma unroll
            for (int n = 0; n < 9; ++n) {
                const int brow = n * 16 + (lane & 15);
                const bf16x8 b = *(const bf16x8*)(sB + brow * LDA + kk * 64 + koff);
                acc[n] = __builtin_amdgcn_mfma_f32_16x16x32_bf16(au.v, b, acc[n], 0, 0, 0);
            }
        }

        const int rbase = rowBase + w * 16 + (lane >> 4) * 4;
#pragma unroll
        for (int n = 0; n < 8; ++n) {
            const int cc = n * 16 + (lane & 15);
#pragma unroll
            for (int r = 0; r < 4; ++r) {
                const int rw = rbase + r;
                if (rw < NN) hb[(size_t)rw * OC + cc] = __float2bfloat16(acc[n][r]);
            }
        }
        const int cp = lane & 15;
        if (cp < 8) {
            const int hd = cp & 3;
            float* dst = (cp < 4) ? al : ar;
#pragma unroll
            for (int r = 0; r < 4; ++r) {
                const int rw = rbase + r;
                if (rw < NN) dst[rw * NH + hd] = acc[8][r];
            }
        }
    } else {
        // ---- part1 path: coarse partition into bin-grouped packed words ----
        int* h     = (int*)smem;
        int* gbase = h + NBIN;
        int* lcur  = gbase + NBIN;
        const int pb = blockIdx.x / 5;    // 0..390
        const int t = tid;
        for (int i = t; i < NBIN; i += 256) { h[i] = 0; lcur[i] = 0; }
        __syncthreads();

        const int e0 = pb * EPB + t * EPT;
        int r[EPT], c[EPT];
        if (e0 + EPT <= NE) {
#pragma unroll
            for (int q = 0; q < EPT / 4; ++q) {
                const int4 rv = *(const int4*)&row[e0 + q * 4];
                const int4 cv = *(const int4*)&col[e0 + q * 4];
                r[q*4+0] = rv.x; r[q*4+1] = rv.y; r[q*4+2] = rv.z; r[q*4+3] = rv.w;
                c[q*4+0] = cv.x; c[q*4+1] = cv.y; c[q*4+2] = cv.z; c[q*4+3] = cv.w;
            }
        } else {
#pragma unroll
            for (int i = 0; i < EPT; ++i) {
                const int e = e0 + i;
                r[i] = (e < NE) ? row[e] : -1;
                c[i] = (e < NE) ? col[e] : 0;
            }
        }
#pragma unroll
        for (int i = 0; i < EPT; ++i)
            if (r[i] >= 0) atomicAdd(&h[r[i] >> BSH], 1);
        __syncthreads();
        for (int i = t; i < NBIN; i += 256)
            if (h[i]) gbase[i] = atomicAdd(&bincur[i], h[i]);
        __syncthreads();
#pragma unroll
        for (int i = 0; i < EPT; ++i) {
            if (r[i] < 0) continue;
            const int b = r[i] >> BSH;
            const int pos = atomicAdd(&lcur[b], 1);
            tmp[gbase[b] + pos] =
                ((unsigned)(r[i] & (BINW - 1)) << 17) | (unsigned)c[i];
        }
    }
}

// Fused fine-partition + aggregation: one 512-thread block per bin.
__global__ __launch_bounds__(512) void k_p2agg(
    const unsigned* __restrict__ tmp, const int* __restrict__ bincur,
    const float* __restrict__ al, const float* __restrict__ ar,
    const __hip_bfloat16* __restrict__ hb, float* __restrict__ out) {
    __shared__ __align__(16) unsigned stage[CAPB];      // 10.2 KB
    __shared__ __align__(16) int scols[SCOLS_CAP];      // 12.0 KB
    __shared__ int h[BINW], st[BINW], cur[BINW], ts[BINW];
    const int b = blockIdx.x;
    const int t = threadIdx.x;                          // 0..511
    const int gs = b * CAPB;
    const int cnt = bincur[b] - gs;

    if (t < BINW) h[t] = 0;
    __syncthreads();
    for (int j = t; j < cnt; j += 512) {
        const unsigned p = tmp[gs + j];
        stage[j] = p;
        atomicAdd(&h[p >> 17], 1);
    }
    __syncthreads();
    if (t < BINW) ts[t] = (h[t] + 3) & ~3;
    __syncthreads();
    for (int o = 1; o < BINW; o <<= 1) {
        const int add = (t >= o && t < BINW) ? ts[t - o] : 0;
        __syncthreads();
        if (t < BINW) ts[t] += add;
        __syncthreads();
    }
    if (t < BINW) {
        const int s = ts[t] - ((h[t] + 3) & ~3);
        st[t] = s;
        cur[t] = s;
    }
    __syncthreads();
    for (int j = t; j < cnt; j += 512) {
        const unsigned p = stage[j];
        const int pos = atomicAdd(&cur[p >> 17], 1);
        scols[pos] = (int)(p & 0x1FFFFu);
    }
    __syncthreads();

    const int w = t >> 6;
    const int lane = t & 63;
    const int g = lane >> 4;
    const int sl = lane & 15;
    const int hsel = sl >> 2;
    const int je = sl >> 2;
    const int sh = sl & 3;
    const int sbase = lane & 48;
    const char* hrow = (const char*)hb + sl * 16;

    for (int rnd = 0; rnd < BINW / 32; ++rnd) {
        const int ln = rnd * 32 + w * 4 + g;
        const int node = b * BINW + ln;
        if (node >= NN) continue;
        const int start = st[ln];
        const int deg = h[ln];
        const float al_sh = al[node * NH + sh];

        f32x2 a0 = {0.f, 0.f}, a1 = {0.f, 0.f}, a2 = {0.f, 0.f}, a3 = {0.f, 0.f};
        float ssum = 0.f;

        int4 cA = *(const int4*)(scols + start);
        int4 cB = *(const int4*)(scols + start + 4);

        for (int kk = 0; kk < deg; kk += 8) {
            const int rem = deg - kk;
            const int4 cA2 = *(const int4*)(scols + start + kk + 8);
            const int4 cB2 = *(const int4*)(scols + start + kk + 12);

            float wvA = 0.f, wvB = 0.f;
            if (je < rem) {
                const int c = sel4(cA, je);
                wvA = __expf(lrelu(al_sh + ar[c * NH + sh]));
            }
            if (je + 4 < rem) {
                const int c = sel4(cB, je);
                wvB = __expf(lrelu(al_sh + ar[c * NH + sh]));
            }

            int c_[8] = {cA.x, cA.y, cA.z, cA.w, cB.x, cB.y, cB.z, cB.w};
#pragma unroll
            for (int j = 0; j < 8; ++j)
                if (j >= rem) c_[j] = 0;

#pragma unroll
            for (int j = 0; j < 8; ++j) {
                const float wj = __shfl(j < 4 ? wvA : wvB, sbase + (j & 3) * 4 + hsel);
                const uint4 v = *(const uint4*)(hrow + (size_t)c_[j] * 256);
                a0 += wj * (f32x2){__uint_as_float(v.x << 16), __uint_as_float(v.x & 0xffff0000u)};
                a1 += wj * (f32x2){__uint_as_float(v.y << 16), __uint_as_float(v.y & 0xffff0000u)};
                a2 += wj * (f32x2){__uint_as_float(v.z << 16), __uint_as_float(v.z & 0xffff0000u)};
                a3 += wj * (f32x2){__uint_as_float(v.w << 16), __uint_as_float(v.w & 0xffff0000u)};
                ssum += wj;
            }
            cA = cA2; cB = cB2;
        }

        const float inv = (ssum > 0.f) ? 1.0f / ssum : 0.f;
        float4 o0, o1;
        o0.x = a0.x * inv; o0.y = a0.y * inv; o0.z = a1.x * inv; o0.w = a1.y * inv;
        o1.x = a2.x * inv; o1.y = a2.y * inv; o1.z = a3.x * inv; o1.w = a3.y * inv;
        float* dst = out + (size_t)node * OC + sl * 8;
        *(float4*)dst = o0;
        *(float4*)(dst + 4) = o1;
    }
}

extern "C" void kernel_launch(void* const* d_in, const int* in_sizes, int n_in,
                              void* d_out, int out_size, void* d_ws, size_t ws_size,
                              hipStream_t stream) {
    const float* x    = (const float*)d_in[0];
    const int*   ei   = (const int*)d_in[1];    // [2, NE]
    const float* W    = (const float*)d_in[2];
    const float* a_l  = (const float*)d_in[3];
    const float* a_r  = (const float*)d_in[4];
    float* out = (float*)d_out;

    const int* row = ei;         // destination
    const int* col = ei + NE;    // source

    char* ws = (char*)d_ws;
    __hip_bfloat16* hb = (__hip_bfloat16*)ws;   ws += (size_t)NN * OC * 2;      // 25.6 MB
    __hip_bfloat16* Wt = (__hip_bfloat16*)ws;   ws += (size_t)144 * 128 * 2;    // 36 KB
    float*    al      = (float*)ws;             ws += (size_t)NN * NH * 4;
    float*    ar      = (float*)ws;             ws += (size_t)NN * NH * 4;
    unsigned* tmp     = (unsigned*)ws;          ws += (size_t)NBIN * CAPB * 4;  // 8.0 MB
    int*      bincur  = (int*)ws;               ws += (size_t)NBIN * 4;

    k_pre<<<72, 256, 0, stream>>>(W, a_l, a_r, Wt, bincur);
    k_gp1<<<1955, 256, 0, stream>>>(x, Wt, hb, al, ar, row, col, bincur, tmp);
    k_p2agg<<<NBIN, 512, 0, stream>>>(tmp, bincur, al, ar, hb, out);
}